// Round 10
// baseline (4265.782 us; speedup 1.0000x reference)
//
#include <hip/hip_runtime.h>
#include <hip/hip_fp16.h>

// A-SNN forward: B=64, T=512, I=O=1024, A=3.
//   init_w1:  fp32->fp16 [ww_x;wb_x] for gemm1
//   gemm1:    XW[t*64+b][0:2048] = x @ [ww_x;wb_x]^T + bias   (MFMA 16x16x32 f16)
//   init_w2p: fragment-packed fp16 recurrent weights W2P
//   xa_proj:  XA = x @ wa_x^T + ba
//   scan:     256 WGs = 8 batch-domains x 32 col-groups; weights in AGPR/VGPR
//             (K-split across 4 waves). r5 protocol verbatim (proven best):
//               h store (packed fp16, sc1) -> vmcnt(0) ACK -> per-wave flag ->
//               slim contiguous flag poll -> bulk fp16 load.
//             r10 changes (stall removal only, no protocol change):
//               - 8x unrolled step with ping-ponged gate-prefetch register sets:
//                 prefetch issues with NO wait; drained by the NEXT step's poll
//                 vmcnt(0) (~2000cy later, fully hidden). No tail waitcnt.
//               - out[] stores batched 8-per-flush in named registers.
//               - no Bf pin asm (compiler places weights in AGPRs), no tags,
//                 no probe/dual-path.

#define B_ 64
#define T_ 512
#define I_ 1024
#define O_ 1024

typedef __attribute__((ext_vector_type(8))) _Float16 half8;
typedef __attribute__((ext_vector_type(4))) float f32x4;
typedef __attribute__((ext_vector_type(4))) float float4v;
typedef __attribute__((ext_vector_type(2))) float float2v;
typedef __attribute__((ext_vector_type(4))) unsigned int uint4v;
typedef __attribute__((ext_vector_type(2))) unsigned int uint2v;

__device__ __forceinline__ float sigm_f(float x) { return 1.f / (1.f + __expf(-x)); }
__device__ __forceinline__ float tanh_f(float x) { return 1.f - 2.f / (1.f + __expf(2.f * x)); }
__device__ __forceinline__ float h2f_bits(unsigned u) {
    union { unsigned short s; _Float16 h; } x; x.s = (unsigned short)u; return (float)x.h;
}

// ---------------- workspace layout (bytes) ----------------
#define WS_XW    0                 // [32768][2048] f16 = 134,217,728
#define WS_W1    134217728         // [2048][1024] f16 (dead after gemm1)
#define WS_W2P   134217728         // 2,621,440 halves = 5,242,880 B (overlays W1)
#define WS_XA    139460608         // [32768][3] f32 = 393,216
#define WS_HBUF  139853824         // [2][64][512] u32 = 262,144 (packed fp16 h)
#define WS_FLG   140116000         // align16 below; [2][8][128] u32 = 8,192
#define WS_FLG_A 140116096         // 16-aligned flag base
#define FLG_BYTES 8192
// total ~140,124,288 (< proven 143,427,584)

// ======================= init: W1 =======================
__global__ void init_w1(const float* __restrict__ ww_x, const float* __restrict__ wb_x,
                        _Float16* __restrict__ W1) {
    const int total = 2048 * 1024;
    for (int idx = blockIdx.x * blockDim.x + threadIdx.x; idx < total;
         idx += gridDim.x * blockDim.x) {
        int n = idx >> 10, i = idx & 1023;
        float v = (n < 1024) ? ww_x[n * 1024 + i] : wb_x[(n - 1024) * 1024 + i];
        W1[idx] = (_Float16)v;
    }
}

// ======================= init: fragment-packed recurrent weights =======================
// idx = ((((g*4+w)*5 + tile)*8 + ktl)*64 + lane)*8 + j
// row r = tile*16 + (lane&15); k = w*256 + ktl*32 + (lane>>4)*8 + j
__global__ void init_w2p(const float* __restrict__ ww_y, const float* __restrict__ wb_y,
                         const float* __restrict__ wa_y, _Float16* __restrict__ W2P) {
    const int total = 32 * 4 * 5 * 8 * 64 * 8;  // 2,621,440
    for (int idx = blockIdx.x * blockDim.x + threadIdx.x; idx < total;
         idx += gridDim.x * blockDim.x) {
        int j = idx & 7;
        int lane = (idx >> 3) & 63;
        int ktl = (idx >> 9) & 7;
        int rest = idx >> 12;          // (g*4+w)*5 + tile
        int tile = rest % 5;
        int gw = rest / 5;
        int w = gw & 3, g = gw >> 2;
        int frow = lane & 15, fch = lane >> 4;
        int r = tile * 16 + frow;
        int k = w * 256 + ktl * 32 + fch * 8 + j;
        float v = 0.f;
        if (r < 32)      v = ww_y[(g * 32 + r) * 1024 + k];
        else if (r < 64) v = wb_y[(g * 32 + r - 32) * 1024 + k];
        else if (r < 67) v = wa_y[(r - 64) * 1024 + k];
        W2P[idx] = (_Float16)v;
    }
}

// ======================= gemm1: input projections =======================
__global__ __launch_bounds__(256) void gemm1(const float* __restrict__ x,
                                             const _Float16* __restrict__ W1,
                                             const float* __restrict__ bw,
                                             const float* __restrict__ bb,
                                             _Float16* __restrict__ XW) {
    __shared__ _Float16 At[2][128][40];
    __shared__ _Float16 Bt[2][128][40];
    const int tid = threadIdx.x;
    const int lane = tid & 63, wid = tid >> 6;
    const int wr = wid >> 1, wc = wid & 1;
    const int ntile = blockIdx.x & 15;
    const int mtile = blockIdx.x >> 4;
    const long m0 = (long)mtile * 128;
    const int n0 = ntile * 128;

    const int r = tid >> 1, hf = tid & 1;
    const int bidx = (int)((m0 + r) & 63);
    const int tt = (int)((m0 + r) >> 6);
    const float* xrow = x + ((size_t)bidx * T_ + tt) * I_ + hf * 16;
    const _Float16* brow = W1 + (size_t)(n0 + r) * 1024 + hf * 16;

    float4v av[4];
    uint4v bv[2];
    auto stage_regs = [&](int kt) {
        const float4v* pa = (const float4v*)(xrow + kt * 32);
        av[0] = pa[0]; av[1] = pa[1]; av[2] = pa[2]; av[3] = pa[3];
        const uint4v* pb = (const uint4v*)(brow + kt * 32);
        bv[0] = pb[0]; bv[1] = pb[1];
    };
    auto write_lds = [&](int buf) {
        union { _Float16 h[16]; half8 v[2]; } u;
        #pragma unroll
        for (int q = 0; q < 4; ++q)
            #pragma unroll
            for (int c = 0; c < 4; ++c) u.h[q * 4 + c] = (_Float16)av[q][c];
        half8* dA = (half8*)&At[buf][r][hf * 16];
        dA[0] = u.v[0]; dA[1] = u.v[1];
        uint4v* dB = (uint4v*)&Bt[buf][r][hf * 16];
        dB[0] = bv[0]; dB[1] = bv[1];
    };

    f32x4 acc[4][4];
    #pragma unroll
    for (int i = 0; i < 4; ++i)
        #pragma unroll
        for (int j = 0; j < 4; ++j) acc[i][j] = (f32x4){0.f, 0.f, 0.f, 0.f};

    const int frow = lane & 15, fch = lane >> 4;
    auto compute = [&](int buf) {
        half8 a[4], b[4];
        #pragma unroll
        for (int i = 0; i < 4; ++i)
            a[i] = *(const half8*)&At[buf][wr * 64 + i * 16 + frow][fch * 8];
        #pragma unroll
        for (int j = 0; j < 4; ++j)
            b[j] = *(const half8*)&Bt[buf][wc * 64 + j * 16 + frow][fch * 8];
        #pragma unroll
        for (int i = 0; i < 4; ++i)
            #pragma unroll
            for (int j = 0; j < 4; ++j)
                acc[i][j] = __builtin_amdgcn_mfma_f32_16x16x32_f16(a[i], b[j], acc[i][j], 0, 0, 0);
    };

    stage_regs(0);
    write_lds(0);
    __syncthreads();
    for (int kt = 0; kt < 32; ++kt) {
        const int cur = kt & 1;
        if (kt < 31) stage_regs(kt + 1);
        compute(cur);
        if (kt < 31) { write_lds(cur ^ 1); __syncthreads(); }
    }

    const int orow = (lane >> 4) * 4, ocol = lane & 15;
    #pragma unroll
    for (int j = 0; j < 4; ++j) {
        const int n = n0 + wc * 64 + j * 16 + ocol;
        const float bias = (n < 1024) ? bw[n] : bb[n - 1024];
        #pragma unroll
        for (int i = 0; i < 4; ++i) {
            const long mb = m0 + wr * 64 + i * 16 + orow;
            #pragma unroll
            for (int rr = 0; rr < 4; ++rr)
                XW[(size_t)(mb + rr) * 2048 + n] = (_Float16)(acc[i][j][rr] + bias);
        }
    }
}

// ======================= xa projection =======================
__global__ __launch_bounds__(256) void xa_proj(const float* __restrict__ x,
                                               const float* __restrict__ wa_x,
                                               const float* __restrict__ ba,
                                               float* __restrict__ XA) {
    const int wid = threadIdx.x >> 6, lane = threadIdx.x & 63;
    const long m = (long)blockIdx.x * 4 + wid;
    const int b = (int)(m & 63), t = (int)(m >> 6);
    const float4v* xr = (const float4v*)(x + ((size_t)b * T_ + t) * I_);
    const float4v* w0 = (const float4v*)(wa_x);
    const float4v* w1 = (const float4v*)(wa_x + 1024);
    const float4v* w2 = (const float4v*)(wa_x + 2048);
    float a0 = 0.f, a1 = 0.f, a2 = 0.f;
    #pragma unroll
    for (int j = 0; j < 4; ++j) {
        const int idx = j * 64 + lane;
        float4v xv = xr[idx];
        float4v v0 = w0[idx], v1 = w1[idx], v2 = w2[idx];
        a0 += xv[0] * v0[0] + xv[1] * v0[1] + xv[2] * v0[2] + xv[3] * v0[3];
        a1 += xv[0] * v1[0] + xv[1] * v1[1] + xv[2] * v1[2] + xv[3] * v1[3];
        a2 += xv[0] * v2[0] + xv[1] * v2[1] + xv[2] * v2[2] + xv[3] * v2[3];
    }
    #pragma unroll
    for (int mset = 32; mset >= 1; mset >>= 1) {
        a0 += __shfl_xor(a0, mset);
        a1 += __shfl_xor(a1, mset);
        a2 += __shfl_xor(a2, mset);
    }
    if (lane == 0) {
        XA[m * 3 + 0] = a0 + ba[0];
        XA[m * 3 + 1] = a1 + ba[1];
        XA[m * 3 + 2] = a2 + ba[2];
    }
}

// ======================= scan =======================
// One step of the recurrence. CUR gate regs were prefetched LAST step (raw asm,
// no wait) and are guaranteed complete by THIS step's poll vmcnt(0); the empty
// asm re-def after the poll pins that ordering (compiler cannot hoist the use).
// NXT gate regs are prefetched here with no wait.
#define STEP(T, CXW, CXB, CA01, CA2, NXW, NXB, NA01, NA2, YB) do {             \
    const int t_ = (T);                                                        \
    const int par_ = t_ & 1;                                                   \
    f32x4 acc_[5];                                                             \
    _Pragma("unroll")                                                          \
    for (int tl = 0; tl < 5; ++tl) acc_[tl] = (f32x4){0.f, 0.f, 0.f, 0.f};     \
    uint4v aq_[8];                                                             \
    _Pragma("unroll")                                                          \
    for (int f = 0; f < 8; ++f) aq_[f] = (uint4v){0u, 0u, 0u, 0u};             \
    if (t_ > 0) {                                                              \
        const int parp_ = (t_ - 1) & 1;                                        \
        const unsigned tg_ = (unsigned)t_;                                     \
        /* slim flag poll: 128 contiguous flags, dwordx2 per lane */           \
        const unsigned* fp2_ = FLG + ((size_t)parp_ * 8 + d) * 128 + (lane << 1); \
        uint2v fv_;                                                            \
        do {                                                                   \
            asm volatile("global_load_dwordx2 %0, %1, off sc0 sc1\n\t"         \
                         "s_waitcnt vmcnt(0)"                                  \
                         : "=v"(fv_) : "v"(fp2_) : "memory");                  \
        } while (__any((int)(fv_[0] < tg_ || fv_[1] < tg_)));                  \
        /* bulk h load: 8 x dwordx4 per frow<8 lane (plain fp16) */            \
        if (frow < 8) {                                                        \
            const _Float16* hp_ = Hh + ((size_t)parp_ * 64 + b0 + frow) * 1024 \
                                  + w * 256 + fch * 8;                         \
            asm volatile(                                                      \
                "global_load_dwordx4 %0, %8, off sc0 sc1\n\t"                  \
                "global_load_dwordx4 %1, %8, off offset:64 sc0 sc1\n\t"        \
                "global_load_dwordx4 %2, %8, off offset:128 sc0 sc1\n\t"       \
                "global_load_dwordx4 %3, %8, off offset:192 sc0 sc1\n\t"       \
                "global_load_dwordx4 %4, %8, off offset:256 sc0 sc1\n\t"       \
                "global_load_dwordx4 %5, %8, off offset:320 sc0 sc1\n\t"       \
                "global_load_dwordx4 %6, %8, off offset:384 sc0 sc1\n\t"       \
                "global_load_dwordx4 %7, %8, off offset:448 sc0 sc1\n\t"       \
                "s_waitcnt vmcnt(0)"                                           \
                : "=&v"(aq_[0]), "=&v"(aq_[1]), "=&v"(aq_[2]), "=&v"(aq_[3]),  \
                  "=&v"(aq_[4]), "=&v"(aq_[5]), "=&v"(aq_[6]), "=&v"(aq_[7])   \
                : "v"(hp_) : "memory");                                        \
        }                                                                      \
        _Pragma("unroll")                                                      \
        for (int f = 0; f < 8; ++f) {                                          \
            union { uint4v u; half8 h; } ua_; ua_.u = aq_[f];                  \
            _Pragma("unroll")                                                  \
            for (int tl = 0; tl < 5; ++tl)                                     \
                acc_[tl] = __builtin_amdgcn_mfma_f32_16x16x32_f16(             \
                    ua_.h, Bf[tl][f], acc_[tl], 0, 0, 0);                      \
        }                                                                      \
    }                                                                          \
    /* pin CUR gate regs after the poll (their loads are drained by it) */     \
    asm volatile("" : "+v"(CXW), "+v"(CXB), "+v"(CA01), "+v"(CA2));            \
    /* cross-wave K-reduce via LDS (C rows 0..7 live in lanes 0..31) */        \
    if (t_ > 0 && hi < 2) {                                                    \
        _Pragma("unroll")                                                      \
        for (int tl = 0; tl < 5; ++tl)                                         \
            *(f32x4*)&PR[par_][w][tl][col][hi * 4] = acc_[tl];                 \
    }                                                                          \
    __syncthreads();                                                           \
    float gw_ = 0.f, gb_ = 0.f, pav_ = 0.f;                                    \
    if (t_ > 0) {                                                              \
        const int tw_ = nn >> 4, c_ = nn & 15, ac_ = nn & 3;                   \
        _Pragma("unroll")                                                      \
        for (int ww_ = 0; ww_ < 4; ++ww_) {                                    \
            gw_ += PR[par_][ww_][tw_][c_][bl];                                 \
            gb_ += PR[par_][ww_][2 + tw_][c_][bl];                             \
            pav_ += PR[par_][ww_][4][ac_][bl];                                 \
        }                                                                      \
    }                                                                          \
    const float pa0_ = __shfl(pav_, (lane & 32) + 0);                          \
    const float pa1_ = __shfl(pav_, (lane & 32) + 1);                          \
    const float pa2_ = __shfl(pav_, (lane & 32) + 2);                          \
    const float wv_ = sigm_f(h2f_bits(CXW) + gw_);                             \
    const float bgt_ = tanh_f(h2f_bits(CXB) + gb_);                            \
    const float wa0_ = sigm_f(CA01[0] + pa0_);                                 \
    const float wa1_ = sigm_f(CA01[1] + pa1_);                                 \
    const float wa2_ = sigm_f(CA2 + pa2_);                                     \
    y = wv_ * y + bgt_;                                                        \
    y = (y >= 0.f) ? y : 0.01f * y;                                            \
    const float th_ = tanh_f(y);                                               \
    const float sp_ = (y > 20.f) ? y : __logf(1.f + __expf(y));                \
    const float h_ = tanh_f(0.1f * (y * wa0_ + th_ * wa1_ + sp_ * wa2_));      \
    /* h store (packed fp16 pairs) -> ACK -> per-wave flag */                  \
    {                                                                          \
        _Float16 hh_ = (_Float16)h_;                                           \
        union { _Float16 x; unsigned short s; } hb_; hb_.x = hh_;              \
        const unsigned hu_ = hb_.s;                                            \
        const unsigned prt_ = (unsigned)__shfl_xor((int)hu_, 1);               \
        if (!(nn & 1)) {                                                       \
            const unsigned pk_ = hu_ | (prt_ << 16);                           \
            unsigned* ha_ = Hbuf + ((size_t)par_ * 64 + b0 + bl) * 512         \
                            + ((n0 + nn) >> 1);                                \
            asm volatile("global_store_dword %0, %1, off sc0 sc1"              \
                         :: "v"(ha_), "v"(pk_) : "memory");                    \
        }                                                                      \
        asm volatile("s_waitcnt vmcnt(0)" ::: "memory");                       \
        if (lane == 0) {                                                       \
            unsigned* fa_ = FLG + ((size_t)par_ * 8 + d) * 128 + (g << 2) + w; \
            const unsigned fvv_ = (unsigned)(t_ + 1);                          \
            asm volatile("global_store_dword %0, %1, off sc0 sc1"              \
                         :: "v"(fa_), "v"(fvv_) : "memory");                   \
        }                                                                      \
    }                                                                          \
    /* gate prefetch for t+1: raw asm, NO wait (drained by next step's poll) */\
    if (t_ + 1 < T_) {                                                         \
        const unsigned short* pxw_ = xwp + (size_t)(t_ + 1) * 131072;          \
        const float* pxa_ = xap + (size_t)(t_ + 1) * 192;                      \
        asm volatile("global_load_ushort %0, %4, off\n\t"                      \
                     "global_load_ushort %1, %4, off offset:2048\n\t"          \
                     "global_load_dwordx2 %2, %5, off\n\t"                     \
                     "global_load_dword %3, %5, off offset:8"                  \
                     : "=&v"(NXW), "=&v"(NXB), "=&v"(NA01), "=&v"(NA2)         \
                     : "v"(pxw_), "v"(pxa_) : "memory");                       \
    }                                                                          \
    YB = h_;                                                                   \
} while (0)

__global__ __launch_bounds__(256, 1) void scan_kernel(
    const _Float16* __restrict__ XW, const float* __restrict__ XA,
    const _Float16* __restrict__ W2P,
    float* __restrict__ out, float* __restrict__ yfin,
    unsigned int* __restrict__ Hbuf, unsigned int* __restrict__ FLG) {
    // [par][wave][tile][col16][row8 pad12] f32
    __shared__ __align__(16) float PR[2][4][5][16][12];

    const int tid = threadIdx.x;
    const int lane = tid & 63, w = tid >> 6;
    const int d = blockIdx.x & 7, g = blockIdx.x >> 3;
    const int b0 = d * 8, n0 = g * 32;
    const int bl = tid >> 5;       // 0..7 local batch (gate layout)
    const int nn = tid & 31;       // 0..31 local col
    const int frow = lane & 15, fch = lane >> 4;
    const int hi = lane >> 4, col = lane & 15;

    // -------- recurrent weights -> registers (fragment-packed; compiler is
    //          free to allocate them in AGPRs — no pin asm) --------
    half8 Bf[5][8];
    {
        const _Float16* wp = W2P + ((size_t)(g * 4 + w) * 40 * 64 + lane) * 8;
        #pragma unroll
        for (int tile = 0; tile < 5; ++tile)
            #pragma unroll
            for (int ktl = 0; ktl < 8; ++ktl)
                Bf[tile][ktl] = *(const half8*)(wp + (size_t)(tile * 8 + ktl) * 512);
    }

    const _Float16* Hh = (const _Float16*)Hbuf;
    const unsigned short* xwp = (const unsigned short*)XW + (size_t)(b0 + bl) * 2048 + n0 + nn;
    const float* xap = XA + (size_t)(b0 + bl) * 3;

    // ping-pong gate register sets (set0 = even steps, set1 = odd steps)
    unsigned g0xw = xwp[0], g0xb = xwp[1024];
    float2v g0a01 = (float2v){xap[0], xap[1]};
    float g0a2 = xap[2];
    unsigned g1xw = 0, g1xb = 0;
    float2v g1a01 = (float2v){0.f, 0.f};
    float g1a2 = 0.f;

    float yb0, yb1, yb2, yb3, yb4, yb5, yb6, yb7;
    float y = 0.f;

    for (int t8 = 0; t8 < 64; ++t8) {
        const int tb = t8 * 8;
        STEP(tb + 0, g0xw, g0xb, g0a01, g0a2, g1xw, g1xb, g1a01, g1a2, yb0);
        STEP(tb + 1, g1xw, g1xb, g1a01, g1a2, g0xw, g0xb, g0a01, g0a2, yb1);
        STEP(tb + 2, g0xw, g0xb, g0a01, g0a2, g1xw, g1xb, g1a01, g1a2, yb2);
        STEP(tb + 3, g1xw, g1xb, g1a01, g1a2, g0xw, g0xb, g0a01, g0a2, yb3);
        STEP(tb + 4, g0xw, g0xb, g0a01, g0a2, g1xw, g1xb, g1a01, g1a2, yb4);
        STEP(tb + 5, g1xw, g1xb, g1a01, g1a2, g0xw, g0xb, g0a01, g0a2, yb5);
        STEP(tb + 6, g0xw, g0xb, g0a01, g0a2, g1xw, g1xb, g1a01, g1a2, yb6);
        STEP(tb + 7, g1xw, g1xb, g1a01, g1a2, g0xw, g0xb, g0a01, g0a2, yb7);
        // batched out flush: 8 coalesced stores, drained by the next poll
        float* ob = out + ((size_t)(b0 + bl) * T_ + tb) * O_ + n0 + nn;
        ob[0]        = yb0;
        ob[1 * O_]   = yb1;
        ob[2 * O_]   = yb2;
        ob[3 * O_]   = yb3;
        ob[4 * O_]   = yb4;
        ob[5 * O_]   = yb5;
        ob[6 * O_]   = yb6;
        ob[7 * O_]   = yb7;
    }
    yfin[(size_t)(b0 + bl) * O_ + n0 + nn] = y;
}

// ======================= launch =======================
extern "C" void kernel_launch(void* const* d_in, const int* in_sizes, int n_in,
                              void* d_out, int out_size, void* d_ws, size_t ws_size,
                              hipStream_t stream) {
    const float* x    = (const float*)d_in[0];
    const float* ww_x = (const float*)d_in[1];
    const float* ww_y = (const float*)d_in[2];
    const float* bw   = (const float*)d_in[3];
    const float* wb_x = (const float*)d_in[4];
    const float* wb_y = (const float*)d_in[5];
    const float* bb   = (const float*)d_in[6];
    const float* wa_x = (const float*)d_in[7];
    const float* wa_y = (const float*)d_in[8];
    const float* ba   = (const float*)d_in[9];

    char* ws = (char*)d_ws;
    _Float16* XW  = (_Float16*)(ws + WS_XW);
    _Float16* W1  = (_Float16*)(ws + WS_W1);
    _Float16* W2P = (_Float16*)(ws + WS_W2P);
    float* XA = (float*)(ws + WS_XA);
    unsigned int* Hbuf = (unsigned int*)(ws + WS_HBUF);
    unsigned int* FLG  = (unsigned int*)(ws + WS_FLG_A);

    float* out = (float*)d_out;
    float* yfin = out + (size_t)B_ * T_ * O_;

    // zero the step flags (prior graph replays leave flags >= T, which would
    // instantly satisfy polls against stale h). Hbuf needs no clear: every
    // read is flag-gated within this launch.
    hipMemsetAsync(ws + WS_FLG_A, 0, FLG_BYTES, stream);
    hipLaunchKernelGGL(init_w1, dim3(2048), dim3(256), 0, stream, ww_x, wb_x, W1);
    hipLaunchKernelGGL(gemm1, dim3(4096), dim3(256), 0, stream, x, W1, bw, bb, XW);
    hipLaunchKernelGGL(init_w2p, dim3(1024), dim3(256), 0, stream, ww_y, wb_y, wa_y, W2P);
    hipLaunchKernelGGL(xa_proj, dim3(8192), dim3(256), 0, stream, x, wa_x, ba, XA);
    hipLaunchKernelGGL(scan_kernel, dim3(256), dim3(256), 0, stream,
                       XW, XA, W2P, out, yfin, Hbuf, FLG);
}

// Round 11
// 2039.878 us; speedup vs baseline: 2.0912x; 2.0912x over previous
//
#include <hip/hip_runtime.h>
#include <hip/hip_fp16.h>

// A-SNN forward: B=64, T=512, I=O=1024, A=3.
//   init_w1:  fp32->fp16 [ww_x;wb_x] for gemm1
//   gemm1:    XW[t*64+b][0:2048] = x @ [ww_x;wb_x]^T + bias   (MFMA 16x16x32 f16)
//             r11: BM=64 x BN=256 tiling (was 128x128) — halves the x re-read
//             factor (16->8 N-tiles), same grid count / blocks-per-CU / 16
//             MFMA-per-kt-per-wave microstructure.
//   init_w2p: fragment-packed fp16 recurrent weights W2P
//   xa_proj:  XA = x @ wa_x^T + ba
//   scan:     r5 kernel VERBATIM (measured best: 1610us): 256 WGs = 8 domains
//             x 32 col-groups, weights in registers, h as packed fp16 pairs,
//             h store -> vmcnt(0) ack -> per-wave flag -> slim dwordx2 poll ->
//             bulk 8x dwordx4 load. r6-r10 protocol mutations all regressed
//             (no-ack -> retry storms; scattered polls -> uncoalesced L3;
//             8x unroll -> I-cache thrash). Do not mutate without A/B.

#define B_ 64
#define T_ 512
#define I_ 1024
#define O_ 1024

typedef __attribute__((ext_vector_type(8))) _Float16 half8;
typedef __attribute__((ext_vector_type(4))) float f32x4;
typedef __attribute__((ext_vector_type(4))) float float4v;
typedef __attribute__((ext_vector_type(4))) unsigned int uint4v;
typedef __attribute__((ext_vector_type(2))) unsigned int uint2v;

__device__ __forceinline__ float sigm_f(float x) { return 1.f / (1.f + __expf(-x)); }
__device__ __forceinline__ float tanh_f(float x) { return 1.f - 2.f / (1.f + __expf(2.f * x)); }
__device__ __forceinline__ float h2f_bits(unsigned short u) {
    union { unsigned short s; _Float16 h; } x; x.s = u; return (float)x.h;
}

// ---------------- workspace layout (bytes) — r5 verbatim ----------------
#define WS_XW    0                 // [32768][2048] f16 = 134,217,728
#define WS_W1    134217728         // [2048][1024] f16 (dead after gemm1)
#define WS_W2P   134217728         // 2,621,440 halves = 5,242,880 B (overlays W1)
#define WS_XA    139460608         // [32768][3] f32 = 393,216
#define WS_HBUF  139853824         // [2][64][1024] f16 = 262,144 (packed pairs)
#define WS_FLG   140115968         // [2][8][128] u32 = 8,192
#define FLG_BYTES 8192
// total 140,124,160 (< proven 143,427,584)

// ======================= init: W1 =======================
__global__ void init_w1(const float* __restrict__ ww_x, const float* __restrict__ wb_x,
                        _Float16* __restrict__ W1) {
    const int total = 2048 * 1024;
    for (int idx = blockIdx.x * blockDim.x + threadIdx.x; idx < total;
         idx += gridDim.x * blockDim.x) {
        int n = idx >> 10, i = idx & 1023;
        float v = (n < 1024) ? ww_x[n * 1024 + i] : wb_x[(n - 1024) * 1024 + i];
        W1[idx] = (_Float16)v;
    }
}

// ======================= init: fragment-packed recurrent weights =======================
// idx = ((((g*4+w)*5 + tile)*8 + ktl)*64 + lane)*8 + j
// row r = tile*16 + (lane&15); k = w*256 + ktl*32 + (lane>>4)*8 + j
__global__ void init_w2p(const float* __restrict__ ww_y, const float* __restrict__ wb_y,
                         const float* __restrict__ wa_y, _Float16* __restrict__ W2P) {
    const int total = 32 * 4 * 5 * 8 * 64 * 8;  // 2,621,440
    for (int idx = blockIdx.x * blockDim.x + threadIdx.x; idx < total;
         idx += gridDim.x * blockDim.x) {
        int j = idx & 7;
        int lane = (idx >> 3) & 63;
        int ktl = (idx >> 9) & 7;
        int rest = idx >> 12;          // (g*4+w)*5 + tile
        int tile = rest % 5;
        int gw = rest / 5;
        int w = gw & 3, g = gw >> 2;
        int frow = lane & 15, fch = lane >> 4;
        int r = tile * 16 + frow;
        int k = w * 256 + ktl * 32 + fch * 8 + j;
        float v = 0.f;
        if (r < 32)      v = ww_y[(g * 32 + r) * 1024 + k];
        else if (r < 64) v = wb_y[(g * 32 + r - 32) * 1024 + k];
        else if (r < 67) v = wa_y[(r - 64) * 1024 + k];
        W2P[idx] = (_Float16)v;
    }
}

// ======================= gemm1: input projections (BM=64, BN=256) =======================
// C[m][n] = sum_k x_row(m)[k] * W1[n][k] + bias(n), m = t*64+b, stored fp16.
// grid = 512 m-tiles x 8 n-tiles = 4096 blocks (16/CU); x re-read factor 8.
__global__ __launch_bounds__(256) void gemm1(const float* __restrict__ x,
                                             const _Float16* __restrict__ W1,
                                             const float* __restrict__ bw,
                                             const float* __restrict__ bb,
                                             _Float16* __restrict__ XW) {
    __shared__ _Float16 At[2][64][40];    // 10,240 B
    __shared__ _Float16 Bt[2][256][40];   // 40,960 B
    const int tid = threadIdx.x;
    const int lane = tid & 63, wid = tid >> 6;
    const int wr = wid >> 1, wc = wid & 1;   // wave grid: 2 (m) x 2 (n)
    const int ntile = blockIdx.x & 7;
    const int mtile = blockIdx.x >> 3;
    const long m0 = (long)mtile * 64;
    const int n0 = ntile * 256;

    // A staging: quarter-row per thread (8 k-floats -> 8 halves)
    const int ar = tid >> 2, aq = tid & 3;
    const int bidx = (int)((m0 + ar) & 63);
    const int tt = (int)((m0 + ar) >> 6);
    const float* xrow = x + ((size_t)bidx * T_ + tt) * I_ + aq * 8;
    // B staging: full row (32 k-halves) per thread
    const _Float16* brow = W1 + (size_t)(n0 + tid) * 1024;

    float4v av[2];
    uint4v bv[4];
    auto stage_regs = [&](int kt) {
        const float4v* pa = (const float4v*)(xrow + kt * 32);
        av[0] = pa[0]; av[1] = pa[1];
        const uint4v* pb = (const uint4v*)(brow + kt * 32);
        bv[0] = pb[0]; bv[1] = pb[1]; bv[2] = pb[2]; bv[3] = pb[3];
    };
    auto write_lds = [&](int buf) {
        union { _Float16 h[8]; half8 v; } u;
        #pragma unroll
        for (int q = 0; q < 2; ++q)
            #pragma unroll
            for (int c = 0; c < 4; ++c) u.h[q * 4 + c] = (_Float16)av[q][c];
        *(half8*)&At[buf][ar][aq * 8] = u.v;
        uint4v* dB = (uint4v*)&Bt[buf][tid][0];
        dB[0] = bv[0]; dB[1] = bv[1]; dB[2] = bv[2]; dB[3] = bv[3];
    };

    f32x4 acc[2][8];
    #pragma unroll
    for (int i = 0; i < 2; ++i)
        #pragma unroll
        for (int j = 0; j < 8; ++j) acc[i][j] = (f32x4){0.f, 0.f, 0.f, 0.f};

    const int frow = lane & 15, fch = lane >> 4;
    auto compute = [&](int buf) {
        half8 a[2], b[8];
        #pragma unroll
        for (int i = 0; i < 2; ++i)
            a[i] = *(const half8*)&At[buf][wr * 32 + i * 16 + frow][fch * 8];
        #pragma unroll
        for (int j = 0; j < 8; ++j)
            b[j] = *(const half8*)&Bt[buf][wc * 128 + j * 16 + frow][fch * 8];
        #pragma unroll
        for (int i = 0; i < 2; ++i)
            #pragma unroll
            for (int j = 0; j < 8; ++j)
                acc[i][j] = __builtin_amdgcn_mfma_f32_16x16x32_f16(a[i], b[j], acc[i][j], 0, 0, 0);
    };

    stage_regs(0);
    write_lds(0);
    __syncthreads();
    for (int kt = 0; kt < 32; ++kt) {
        const int cur = kt & 1;
        if (kt < 31) stage_regs(kt + 1);
        compute(cur);
        if (kt < 31) { write_lds(cur ^ 1); __syncthreads(); }
    }

    const int orow = (lane >> 4) * 4, ocol = lane & 15;
    #pragma unroll
    for (int j = 0; j < 8; ++j) {
        const int n = n0 + wc * 128 + j * 16 + ocol;
        const float bias = (n < 1024) ? bw[n] : bb[n - 1024];
        #pragma unroll
        for (int i = 0; i < 2; ++i) {
            const long mb = m0 + wr * 32 + i * 16 + orow;
            #pragma unroll
            for (int rr = 0; rr < 4; ++rr)
                XW[(size_t)(mb + rr) * 2048 + n] = (_Float16)(acc[i][j][rr] + bias);
        }
    }
}

// ======================= xa projection =======================
__global__ __launch_bounds__(256) void xa_proj(const float* __restrict__ x,
                                               const float* __restrict__ wa_x,
                                               const float* __restrict__ ba,
                                               float* __restrict__ XA) {
    const int wid = threadIdx.x >> 6, lane = threadIdx.x & 63;
    const long m = (long)blockIdx.x * 4 + wid;
    const int b = (int)(m & 63), t = (int)(m >> 6);
    const float4v* xr = (const float4v*)(x + ((size_t)b * T_ + t) * I_);
    const float4v* w0 = (const float4v*)(wa_x);
    const float4v* w1 = (const float4v*)(wa_x + 1024);
    const float4v* w2 = (const float4v*)(wa_x + 2048);
    float a0 = 0.f, a1 = 0.f, a2 = 0.f;
    #pragma unroll
    for (int j = 0; j < 4; ++j) {
        const int idx = j * 64 + lane;
        float4v xv = xr[idx];
        float4v v0 = w0[idx], v1 = w1[idx], v2 = w2[idx];
        a0 += xv[0] * v0[0] + xv[1] * v0[1] + xv[2] * v0[2] + xv[3] * v0[3];
        a1 += xv[0] * v1[0] + xv[1] * v1[1] + xv[2] * v1[2] + xv[3] * v1[3];
        a2 += xv[0] * v2[0] + xv[1] * v2[1] + xv[2] * v2[2] + xv[3] * v2[3];
    }
    #pragma unroll
    for (int mset = 32; mset >= 1; mset >>= 1) {
        a0 += __shfl_xor(a0, mset);
        a1 += __shfl_xor(a1, mset);
        a2 += __shfl_xor(a2, mset);
    }
    if (lane == 0) {
        XA[m * 3 + 0] = a0 + ba[0];
        XA[m * 3 + 1] = a1 + ba[1];
        XA[m * 3 + 2] = a2 + ba[2];
    }
}

// ======================= scan (r5 verbatim — measured best) =======================
__global__ __launch_bounds__(256, 1) void scan_kernel(
    const _Float16* __restrict__ XW, const float* __restrict__ XA,
    const _Float16* __restrict__ W2P,
    float* __restrict__ out, float* __restrict__ yfin,
    unsigned int* __restrict__ Hbuf, unsigned int* __restrict__ FLG) {
    // [par][wave][tile][col16][row8 pad12] f32
    __shared__ __align__(16) float PR[2][4][5][16][12];

    const int tid = threadIdx.x;
    const int lane = tid & 63, w = tid >> 6;
    const int d = blockIdx.x & 7, g = blockIdx.x >> 3;
    const int b0 = d * 8, n0 = g * 32;
    const int bl = tid >> 5;       // 0..7 local batch (gate layout)
    const int nn = tid & 31;       // 0..31 local col
    const int frow = lane & 15, fch = lane >> 4;
    const int hi = lane >> 4, col = lane & 15;

    // -------- recurrent weights -> registers (fragment-packed, pinned) --------
    half8 Bf[5][8];
    {
        const _Float16* wp = W2P + ((size_t)(g * 4 + w) * 40 * 64 + lane) * 8;
        #pragma unroll
        for (int tile = 0; tile < 5; ++tile)
            #pragma unroll
            for (int ktl = 0; ktl < 8; ++ktl)
                Bf[tile][ktl] = *(const half8*)(wp + (size_t)(tile * 8 + ktl) * 512);
    }
    #pragma unroll
    for (int tile = 0; tile < 5; ++tile)
        #pragma unroll
        for (int ktl = 0; ktl < 8; ++ktl)
            asm volatile("" : "+v"(Bf[tile][ktl]));   // pin in VGPRs (defeat remat)

    uint4v aq[8];
    #pragma unroll
    for (int f = 0; f < 8; ++f) aq[f] = (uint4v){0u, 0u, 0u, 0u};

    // gate-input prefetch pointers (per-thread)
    const unsigned short* xwp = (const unsigned short*)XW + (size_t)(b0 + bl) * 2048 + n0 + nn;
    const unsigned short* xbp = xwp + 1024;
    const float* xap = XA + (size_t)(b0 + bl) * 3;

    unsigned short c_xw = xwp[0], c_xb = xbp[0];
    float c_xa0 = xap[0], c_xa1 = xap[1], c_xa2 = xap[2];
    unsigned short n_xw = 0, n_xb = 0;
    float n_xa0 = 0.f, n_xa1 = 0.f, n_xa2 = 0.f;

    const _Float16* Hh = (const _Float16*)Hbuf;

    float y = 0.f;
    for (int t = 0; t < T_; ++t) {
        const int par = t & 1;
        f32x4 acc[5];
        #pragma unroll
        for (int tile = 0; tile < 5; ++tile) acc[tile] = (f32x4){0.f, 0.f, 0.f, 0.f};

        if (t > 0) {
            const int parp = (t - 1) & 1;
            // ---- slim flag poll: 8B per lane per retry ----
            {
                const unsigned need = (unsigned)t;
                const unsigned* fp2 = FLG + ((size_t)parp * 8 + d) * 128 + (lane << 1);
                uint2v fv;
                do {
                    asm volatile("global_load_dwordx2 %0, %1, off sc0 sc1\n\t"
                                 "s_waitcnt vmcnt(0)"
                                 : "=v"(fv) : "v"(fp2) : "memory");
                } while (__any((int)(fv[0] < need || fv[1] < need)));
            }
            // ---- bulk A-fragment load (plain fp16, MFMA layout) ----
            if (frow < 8) {
                const _Float16* hp = Hh + ((size_t)parp * 64 + b0 + frow) * 1024
                                     + w * 256 + fch * 8;
                asm volatile(
                    "global_load_dwordx4 %0, %8, off sc0 sc1\n\t"
                    "global_load_dwordx4 %1, %8, off offset:64 sc0 sc1\n\t"
                    "global_load_dwordx4 %2, %8, off offset:128 sc0 sc1\n\t"
                    "global_load_dwordx4 %3, %8, off offset:192 sc0 sc1\n\t"
                    "global_load_dwordx4 %4, %8, off offset:256 sc0 sc1\n\t"
                    "global_load_dwordx4 %5, %8, off offset:320 sc0 sc1\n\t"
                    "global_load_dwordx4 %6, %8, off offset:384 sc0 sc1\n\t"
                    "global_load_dwordx4 %7, %8, off offset:448 sc0 sc1\n\t"
                    "s_waitcnt vmcnt(0)"
                    : "=&v"(aq[0]), "=&v"(aq[1]), "=&v"(aq[2]), "=&v"(aq[3]),
                      "=&v"(aq[4]), "=&v"(aq[5]), "=&v"(aq[6]), "=&v"(aq[7])
                    : "v"(hp) : "memory");
            }
            #pragma unroll
            for (int f = 0; f < 8; ++f) {
                union { uint4v u; half8 h; } ua;
                ua.u = aq[f];
                #pragma unroll
                for (int tile = 0; tile < 5; ++tile)
                    acc[tile] = __builtin_amdgcn_mfma_f32_16x16x32_f16(ua.h, Bf[tile][f],
                                                                       acc[tile], 0, 0, 0);
            }
        }

        // cross-wave K-reduce via LDS (C rows 0..7 live in lanes 0..31)
        if (t > 0 && hi < 2) {
            #pragma unroll
            for (int tile = 0; tile < 5; ++tile)
                *(f32x4*)&PR[par][w][tile][col][hi * 4] = acc[tile];
        }
        __syncthreads();

        float gw = 0.f, gb = 0.f, pav = 0.f;
        if (t > 0) {
            const int tw = nn >> 4, c = nn & 15, ac = nn & 3;
            #pragma unroll
            for (int ww = 0; ww < 4; ++ww) {
                gw += PR[par][ww][tw][c][bl];
                gb += PR[par][ww][2 + tw][c][bl];
                pav += PR[par][ww][4][ac][bl];
            }
        }
        const float pa0 = __shfl(pav, (lane & 32) + 0);
        const float pa1 = __shfl(pav, (lane & 32) + 1);
        const float pa2 = __shfl(pav, (lane & 32) + 2);

        const float wv = sigm_f(h2f_bits(c_xw) + gw);
        const float bgt = tanh_f(h2f_bits(c_xb) + gb);
        const float wa0 = sigm_f(c_xa0 + pa0);
        const float wa1 = sigm_f(c_xa1 + pa1);
        const float wa2 = sigm_f(c_xa2 + pa2);
        y = wv * y + bgt;
        y = (y >= 0.f) ? y : 0.01f * y;
        const float th = tanh_f(y);
        const float sp = (y > 20.f) ? y : __logf(1.f + __expf(y));
        const float h = tanh_f(0.1f * (y * wa0 + th * wa1 + sp * wa2));

        // ---- h store (plain fp16 pairs, agent scope) ----
        {
            _Float16 hh = (_Float16)h;
            union { _Float16 x; unsigned short s; } hb; hb.x = hh;
            unsigned hu = hb.s;
            const unsigned partner = (unsigned)__shfl_xor((int)hu, 1);
            if (!(nn & 1)) {
                const unsigned packed = hu | (partner << 16);
                __hip_atomic_store(&Hbuf[(size_t)(par * 64 + b0 + bl) * 512 + ((n0 + nn) >> 1)],
                                   packed, __ATOMIC_RELAXED, __HIP_MEMORY_SCOPE_AGENT);
            }
        }
        // per-wave release: wait own stores acked, then publish flag t+1
        asm volatile("s_waitcnt vmcnt(0)" ::: "memory");
        if (lane == 0)
            __hip_atomic_store(&FLG[((size_t)par * 8 + d) * 128 + (g << 2) + w],
                               (unsigned)(t + 1), __ATOMIC_RELAXED, __HIP_MEMORY_SCOPE_AGENT);

        // off the critical path: result store + next-step gate-input prefetch
        out[((size_t)(b0 + bl) * T_ + t) * O_ + n0 + nn] = h;
        if (t + 1 < T_) {
            const size_t o = (size_t)(t + 1) * 131072;
            n_xw = xwp[o];
            n_xb = xbp[o];
            const float* xa = xap + (size_t)(t + 1) * 192;
            n_xa0 = xa[0]; n_xa1 = xa[1]; n_xa2 = xa[2];
        }
        c_xw = n_xw; c_xb = n_xb;
        c_xa0 = n_xa0; c_xa1 = n_xa1; c_xa2 = n_xa2;
    }
    yfin[(size_t)(b0 + bl) * O_ + n0 + nn] = y;
}

// ======================= launch =======================
extern "C" void kernel_launch(void* const* d_in, const int* in_sizes, int n_in,
                              void* d_out, int out_size, void* d_ws, size_t ws_size,
                              hipStream_t stream) {
    const float* x    = (const float*)d_in[0];
    const float* ww_x = (const float*)d_in[1];
    const float* ww_y = (const float*)d_in[2];
    const float* bw   = (const float*)d_in[3];
    const float* wb_x = (const float*)d_in[4];
    const float* wb_y = (const float*)d_in[5];
    const float* bb   = (const float*)d_in[6];
    const float* wa_x = (const float*)d_in[7];
    const float* wa_y = (const float*)d_in[8];
    const float* ba   = (const float*)d_in[9];

    char* ws = (char*)d_ws;
    _Float16* XW  = (_Float16*)(ws + WS_XW);
    _Float16* W1  = (_Float16*)(ws + WS_W1);
    _Float16* W2P = (_Float16*)(ws + WS_W2P);
    float* XA = (float*)(ws + WS_XA);
    unsigned int* Hbuf = (unsigned int*)(ws + WS_HBUF);
    unsigned int* FLG  = (unsigned int*)(ws + WS_FLG);

    float* out = (float*)d_out;
    float* yfin = out + (size_t)B_ * T_ * O_;

    hipMemsetAsync(FLG, 0, FLG_BYTES, stream);
    hipLaunchKernelGGL(init_w1, dim3(2048), dim3(256), 0, stream, ww_x, wb_x, W1);
    hipLaunchKernelGGL(gemm1, dim3(4096), dim3(256), 0, stream, x, W1, bw, bb, XW);
    hipLaunchKernelGGL(init_w2p, dim3(1024), dim3(256), 0, stream, ww_y, wb_y, wa_y, W2P);
    hipLaunchKernelGGL(xa_proj, dim3(8192), dim3(256), 0, stream, x, wa_x, ba, XA);
    hipLaunchKernelGGL(scan_kernel, dim3(256), dim3(256), 0, stream,
                       XW, XA, W2P, out, yfin, Hbuf, FLG);
}